// Round 13
// baseline (1839.692 us; speedup 1.0000x reference)
//
#include <hip/hip_runtime.h>

// ---------------- constants ----------------
#define SQL 2048      // sequence length
#define DIM 512
#define NHEADS 8
#define HD 64         // head dim
#define NLAYERS 4
#define NLEVELS 3
#define HID 2048
#define VOC 50257
#define CHUNK 64
#define NCHUNK 32     // SQL / CHUNK
#define SD (SQL * DIM)
#define DD (DIM * DIM)

typedef __attribute__((ext_vector_type(8))) short bf16x8;   // 8 bf16 = 4 VGPR
typedef __attribute__((ext_vector_type(4))) float f32x4;    // MFMA accumulator

__device__ __forceinline__ float gelu_f(float x) {
    float x3 = x * x * x;
    return 0.5f * x * (1.f + tanhf(0.7978845608028654f * (x + 0.044715f * x3)));
}
// fmap = elu(x)+1 : x>0 ? x+1 : exp(x)
__device__ __forceinline__ float fmap_f(float x) {
    return x > 0.f ? x + 1.f : expf(x);
}
// fp32 -> bf16 round-to-nearest-even
__device__ __forceinline__ unsigned short f2bf(float x) {
    unsigned int u = __float_as_uint(x);
    u = (u + 0x7fffu + ((u >> 16) & 1u)) >> 16;
    return (unsigned short)u;
}
__device__ __forceinline__ float bf2f(unsigned short h) {
    return __uint_as_float(((unsigned int)h) << 16);
}

// ---------------- embedding ----------------
__global__ __launch_bounds__(256) void embed_k(
    const float* __restrict__ tok, const float* __restrict__ pos,
    const int* __restrict__ ids, float* __restrict__ x)
{
    int idx = blockIdx.x * 256 + threadIdx.x;       // 0 .. S*D-1
    int t = idx >> 9;                               // idx / 512
    int d = idx & 511;
    x[idx] = tok[(size_t)ids[t] * DIM + d] + pos[idx];
}

// ---------------- layernorm: fp32 in -> bf16 hi/lo planes out ----------------
__global__ __launch_bounds__(256) void ln_k(
    const float* __restrict__ in, unsigned short* __restrict__ oh,
    unsigned short* __restrict__ ol,
    const float* __restrict__ w, const float* __restrict__ b)
{
    int t = blockIdx.x, tid = threadIdx.x;
    float v0 = in[t * DIM + tid];
    float v1 = in[t * DIM + 256 + tid];
    float s = v0 + v1, sq = v0 * v0 + v1 * v1;
    #pragma unroll
    for (int off = 32; off > 0; off >>= 1) {
        s  += __shfl_down(s, off);
        sq += __shfl_down(sq, off);
    }
    __shared__ float ss[4], sqs[4];
    int wave = tid >> 6, lane = tid & 63;
    if (lane == 0) { ss[wave] = s; sqs[wave] = sq; }
    __syncthreads();
    float S  = ss[0] + ss[1] + ss[2] + ss[3];
    float SQ = sqs[0] + sqs[1] + sqs[2] + sqs[3];
    float m   = S * (1.f / DIM);
    float var = SQ * (1.f / DIM) - m * m;
    float rs  = rsqrtf(var + 1e-5f);
    float y0 = (v0 - m) * rs * w[tid]       + b[tid];
    float y1 = (v1 - m) * rs * w[256 + tid] + b[256 + tid];
    unsigned short h0 = f2bf(y0), h1 = f2bf(y1);
    oh[t * DIM + tid]       = h0;
    ol[t * DIM + tid]       = f2bf(y0 - bf2f(h0));
    oh[t * DIM + 256 + tid] = h1;
    ol[t * DIM + 256 + tid] = f2bf(y1 - bf2f(h1));
}

// ---------------- convert rows, hi plane only: fp32 -> bf16 ----------------
__global__ __launch_bounds__(256) void conv_rh_k(
    const float* __restrict__ in, unsigned short* __restrict__ oh, long long n4)
{
    long long i = (long long)blockIdx.x * 256 + threadIdx.x;
    if (i >= n4) return;
    float4 v = ((const float4*)in)[i];
    ushort4 hh;
    hh.x = f2bf(v.x); hh.y = f2bf(v.y); hh.z = f2bf(v.z); hh.w = f2bf(v.w);
    ((ushort4*)oh)[i] = hh;
}

// ---------------- convert + transpose: fp32 [K][N] -> bf16 hi/lo [N][K] ----------------
// grid: (N/32, K/32, nmat), 256 threads.  srcZ/dstZ: per-z element strides.
__global__ __launch_bounds__(256) void conv_t_k(
    const float* __restrict__ in, unsigned short* __restrict__ oh,
    unsigned short* __restrict__ ol, int K, int N,
    size_t srcZ, size_t dstZ)
{
    in += (size_t)blockIdx.z * srcZ;
    oh += (size_t)blockIdx.z * dstZ;
    ol += (size_t)blockIdx.z * dstZ;
    __shared__ float T[32][33];
    const int n0 = blockIdx.x * 32, k0 = blockIdx.y * 32;
    const int tr = threadIdx.x >> 3, tc = threadIdx.x & 7;   // 32 rows x 8 col-groups
    float4 v = *(const float4*)(in + (size_t)(k0 + tr) * N + n0 + tc * 4);
    T[tr][tc * 4 + 0] = v.x;
    T[tr][tc * 4 + 1] = v.y;
    T[tr][tc * 4 + 2] = v.z;
    T[tr][tc * 4 + 3] = v.w;
    __syncthreads();
    float o0 = T[tc * 4 + 0][tr];
    float o1 = T[tc * 4 + 1][tr];
    float o2 = T[tc * 4 + 2][tr];
    float o3 = T[tc * 4 + 3][tr];
    unsigned short h0 = f2bf(o0), h1 = f2bf(o1), h2 = f2bf(o2), h3 = f2bf(o3);
    ushort4 hh; hh.x = h0; hh.y = h1; hh.z = h2; hh.w = h3;
    ushort4 ll;
    ll.x = f2bf(o0 - bf2f(h0));
    ll.y = f2bf(o1 - bf2f(h1));
    ll.z = f2bf(o2 - bf2f(h2));
    ll.w = f2bf(o3 - bf2f(h3));
    size_t off = (size_t)(n0 + tr) * K + k0 + tc * 4;
    *(ushort4*)(oh + off) = hh;
    *(ushort4*)(ol + off) = ll;
}

// ============ MFMA GEMM (tiled): 128xBN block, 4 waves, LDS-staged ============
// A planes [M][K], B planes [N][K], k-major bf16 hi/lo.  BM=128, BK=32.
// BN = 128 (wave-tile 64x64) or 64 (wave-tile 64x32).
// Reg-staged copy w/ prefetch + T2 chunk-XOR swizzle (R12: conflicts 1.9e7 -> 0).
// THIS ROUND (T4-lite): counted-waitcnt barriers.  hipcc's __syncthreads emits
// s_waitcnt vmcnt(0) lgkmcnt(0) + s_barrier, draining in-flight prefetch loads
// twice per k-step.  Replace with:
//   barrier-1 (before ds_writes): RAW s_barrier.  Safe: every wave's ds_reads
//     were consumed by MFMAs (compiler lgkm-waits) before it arrives; LDS
//     writes follow the barrier, VGPRs are wave-private.
//   barrier-2 (writes->visible): s_waitcnt lgkmcnt(0) ONLY + s_barrier.
//     Global prefetch loads live on vmcnt -> stay in flight across barriers
//     (AITER "never vmcnt(0)" property); compiler still vmcnt-waits right
//     before the ds_write that consumes each staged register.
// sched_barrier(0) fences + "memory" clobbers prevent compiler reordering
// of LDS ops across the raw barriers (guide rule #18).
// History: gload_lds dbuf = neutral (R7); XCD swizzle = regressed (R10);
// LN-fusion = regressed (R9); scan-fusion = regressed (R11).
// X3: include a_lo*b_hi AND a_hi*b_lo (X3=false drops b_lo: 2 MFMAs, no Bl).
// ACT: 0 none, 2 gelu, 3 fmap if (col < fthr).  NG: guard N tail.
// MSWAP: blockIdx.x = M-tile (M-fastest launch order -> B-tile shared in L2).
template<int ACT, bool RES, bool PLANES, bool NG, bool X3, bool MSWAP, int BN>
__global__ __launch_bounds__(256) void gemm_t(
    const unsigned short* __restrict__ Ah, const unsigned short* __restrict__ Al,
    const unsigned short* __restrict__ Bh, const unsigned short* __restrict__ Bl,
    const float* __restrict__ bias, const float* __restrict__ Rsrc,
    float* __restrict__ C, unsigned short* __restrict__ Oh,
    unsigned short* __restrict__ Ol,
    int M, int N, int K, int fthr)
{
    constexpr int NW = BN / 2;      // wave-tile N width (64 or 32)
    constexpr int NF = NW / 16;     // B fragments per wave (4 or 2)
    __shared__ unsigned short sAh[4096], sAl[4096];
    __shared__ unsigned short sBh[BN * 32];
    __shared__ unsigned short sBl[X3 ? BN * 32 : 64];

    const int tid  = threadIdx.x;
    const int w    = tid >> 6, lane = tid & 63;
    const int r    = lane & 15, kq = lane >> 4;
    const int wr   = w >> 1, wc = w & 1;          // 2x2 wave grid
    const int m0   = (MSWAP ? blockIdx.x : blockIdx.y) * 128;
    const int n0   = (MSWAP ? blockIdx.y : blockIdx.x) * BN;

    // staging: A has 512 slots (2/thread: tid, tid+256); B has BN*4 slots.
    const int srow = tid >> 2;          // 0..63
    const int sch  = tid & 3;           // 16B chunk within 64B row
    const int ar0 = m0 + srow, ar1 = ar0 + 64;
    int br0 = n0 + srow;
    if (NG) br0 = br0 < N ? br0 : N - 1;
    const unsigned short* pAh0 = Ah + (size_t)ar0 * K + sch * 8;
    const unsigned short* pAh1 = Ah + (size_t)ar1 * K + sch * 8;
    const unsigned short* pAl0 = Al + (size_t)ar0 * K + sch * 8;
    const unsigned short* pAl1 = Al + (size_t)ar1 * K + sch * 8;
    const unsigned short* pBh0 = Bh + (size_t)br0 * K + sch * 8;
    const unsigned short* pBl0 = X3 ? Bl + (size_t)br0 * K + sch * 8 : nullptr;
    const unsigned short* pBh1 = nullptr;
    const unsigned short* pBl1 = nullptr;
    if constexpr (BN == 128) {
        int br1 = n0 + 64 + srow;
        if (NG) br1 = br1 < N ? br1 : N - 1;
        pBh1 = Bh + (size_t)br1 * K + sch * 8;
        if constexpr (X3) pBl1 = Bl + (size_t)br1 * K + sch * 8;
    }

    // prologue loads (k-step 0)
    bf16x8 rAh0 = *(const bf16x8*)pAh0, rAh1 = *(const bf16x8*)pAh1;
    bf16x8 rAl0 = *(const bf16x8*)pAl0, rAl1 = *(const bf16x8*)pAl1;
    bf16x8 rBh0 = *(const bf16x8*)pBh0;
    bf16x8 rBh1{}, rBl0{}, rBl1{};
    if constexpr (X3) rBl0 = *(const bf16x8*)pBl0;
    if constexpr (BN == 128) {
        rBh1 = *(const bf16x8*)pBh1;
        if constexpr (X3) rBl1 = *(const bf16x8*)pBl1;
    }

    f32x4 acc[4][NF] = {};
    // T2 swizzle: chunk' = chunk ^ ((row>>1)&3).  Row+64 keeps the same key.
    const int sw = srow * 32 + ((sch ^ ((srow >> 1) & 3)) * 8);
    const int kx = (kq ^ ((r >> 1) & 3)) * 8;     // read-side swizzled chunk

    for (int ks = 0; ks < K; ks += 32) {
        // barrier-1: prior reads consumed; RAW barrier, no waitcnt drain.
        __builtin_amdgcn_sched_barrier(0);
        asm volatile("" ::: "memory");
        __builtin_amdgcn_s_barrier();
        asm volatile("" ::: "memory");
        __builtin_amdgcn_sched_barrier(0);

        *(bf16x8*)&sAh[sw] = rAh0;  *(bf16x8*)&sAh[sw + 2048] = rAh1;
        *(bf16x8*)&sAl[sw] = rAl0;  *(bf16x8*)&sAl[sw + 2048] = rAl1;
        *(bf16x8*)&sBh[sw] = rBh0;
        if constexpr (BN == 128) *(bf16x8*)&sBh[sw + 2048] = rBh1;
        if constexpr (X3) {
            *(bf16x8*)&sBl[sw] = rBl0;
            if constexpr (BN == 128) *(bf16x8*)&sBl[sw + 2048] = rBl1;
        }

        // barrier-2: writes visible -- lgkmcnt ONLY (vmcnt loads stay in flight)
        __builtin_amdgcn_sched_barrier(0);
        asm volatile("s_waitcnt lgkmcnt(0)" ::: "memory");
        __builtin_amdgcn_s_barrier();
        asm volatile("" ::: "memory");
        __builtin_amdgcn_sched_barrier(0);

        if (ks + 32 < K) {               // prefetch next k-step (hides under MFMA)
            pAh0 += 32; pAh1 += 32; pAl0 += 32; pAl1 += 32;
            pBh0 += 32;
            rAh0 = *(const bf16x8*)pAh0; rAh1 = *(const bf16x8*)pAh1;
            rAl0 = *(const bf16x8*)pAl0; rAl1 = *(const bf16x8*)pAl1;
            rBh0 = *(const bf16x8*)pBh0;
            if constexpr (X3) { pBl0 += 32; rBl0 = *(const bf16x8*)pBl0; }
            if constexpr (BN == 128) {
                pBh1 += 32; rBh1 = *(const bf16x8*)pBh1;
                if constexpr (X3) { pBl1 += 32; rBl1 = *(const bf16x8*)pBl1; }
            }
        }

        bf16x8 a_h[4], a_l[4];
        #pragma unroll
        for (int mi = 0; mi < 4; ++mi) {
            const int off = (wr * 64 + mi * 16 + r) * 32 + kx;
            a_h[mi] = *(const bf16x8*)&sAh[off];
            a_l[mi] = *(const bf16x8*)&sAl[off];
        }
        #pragma unroll
        for (int ni = 0; ni < NF; ++ni) {
            const int off = (wc * NW + ni * 16 + r) * 32 + kx;
            const bf16x8 b_h = *(const bf16x8*)&sBh[off];
            #pragma unroll
            for (int mi = 0; mi < 4; ++mi) {
                acc[mi][ni] = __builtin_amdgcn_mfma_f32_16x16x32_bf16(
                    a_h[mi], b_h, acc[mi][ni], 0, 0, 0);
                acc[mi][ni] = __builtin_amdgcn_mfma_f32_16x16x32_bf16(
                    a_l[mi], b_h, acc[mi][ni], 0, 0, 0);
            }
            if constexpr (X3) {
                const bf16x8 b_l = *(const bf16x8*)&sBl[off];
                #pragma unroll
                for (int mi = 0; mi < 4; ++mi)
                    acc[mi][ni] = __builtin_amdgcn_mfma_f32_16x16x32_bf16(
                        a_h[mi], b_l, acc[mi][ni], 0, 0, 0);
            }
        }
    }

    // epilogue: C/D layout col = lane&15, row = (lane>>4)*4 + reg  [m89-verified]
    #pragma unroll
    for (int mi = 0; mi < 4; ++mi)
        #pragma unroll
        for (int ni = 0; ni < NF; ++ni) {
            const int nn = n0 + wc * NW + ni * 16 + r;
            if (NG && nn >= N) continue;
            #pragma unroll
            for (int g = 0; g < 4; ++g) {
                const int mm = m0 + wr * 64 + mi * 16 + kq * 4 + g;
                float v = acc[mi][ni][g];
                if (bias) v += bias[nn];
                if (ACT == 2) v = gelu_f(v);
                if (ACT == 3) v = (nn < fthr) ? fmap_f(v) : v;
                const size_t o = (size_t)mm * N + nn;
                if (PLANES) {
                    unsigned short h = f2bf(v);
                    Oh[o] = h;
                    Ol[o] = f2bf(v - bf2f(h));
                } else {
                    if (RES) v += Rsrc[o];
                    C[o] = v;
                }
            }
        }
}

// ============ MFMA GEMM (split-K): 8 waves split K 8-way, LDS reduce ============
// Block = 512 thr = 8 waves (2 waves/SIMD TLP hides reg-direct load latency).
// Requires M%64==0, N%64==0, K%256==0.
// ACT: 0 none, 2 gelu, 3 fmap if (col < fthr).
template<int ACT, bool RES, bool PLANES>
__global__ __launch_bounds__(512) void gemm_ks(
    const unsigned short* __restrict__ Ah, const unsigned short* __restrict__ Al,
    const unsigned short* __restrict__ Bh, const unsigned short* __restrict__ Bl,
    const float* __restrict__ bias, const float* __restrict__ Rsrc,
    float* __restrict__ C, unsigned short* __restrict__ Oh,
    unsigned short* __restrict__ Ol,
    int M, int N, int K, int fthr)
{
    const int tid  = threadIdx.x;
    const int w    = tid >> 6;     // wave 0..7 = K-eighth owner
    const int lane = tid & 63;
    const int r  = lane & 15;
    const int kq = lane >> 4;
    const int m0 = blockIdx.y * 64, n0 = blockIdx.x * 64;
    const int Kw = K >> 3;

    f32x4 acc[4][4] = {};

    size_t aoff[4], boff[4];
    #pragma unroll
    for (int i = 0; i < 4; ++i) {
        aoff[i] = (size_t)(m0 + i * 16 + r) * K + w * Kw + kq * 8;
        boff[i] = (size_t)(n0 + i * 16 + r) * K + w * Kw + kq * 8;
    }

    for (int k0 = 0; k0 < Kw; k0 += 32) {
        bf16x8 ah[4], al4[4], bh[4], bl4[4];
        #pragma unroll
        for (int i = 0; i < 4; ++i) {
            ah[i]  = *(const bf16x8*)(Ah + aoff[i] + k0);
            al4[i] = *(const bf16x8*)(Al + aoff[i] + k0);
            bh[i]  = *(const bf16x8*)(Bh + boff[i] + k0);
            bl4[i] = *(const bf16x8*)(Bl + boff[i] + k0);
        }
        #pragma unroll
        for (int mi = 0; mi < 4; ++mi)
            #pragma unroll
            for (int ni = 0; ni < 4; ++ni) {
                acc[mi][ni] = __builtin_amdgcn_mfma_f32_16x16x32_bf16(
                    ah[mi], bh[ni], acc[mi][ni], 0, 0, 0);
                acc[mi][ni] = __builtin_amdgcn_mfma_f32_16x16x32_bf16(
                    ah[mi], bl4[ni], acc[mi][ni], 0, 0, 0);
                acc[mi][ni] = __builtin_amdgcn_mfma_f32_16x16x32_bf16(
                    al4[mi], bh[ni], acc[mi][ni], 0, 0, 0);
            }
    }

    // ---- cross-wave reduction: two 32-row rounds, XOR-swizzled f32x4 LDS ----
    __shared__ f32x4 red[8][64][8];   // 64 KB

    #pragma unroll
    for (int R = 0; R < 2; ++R) {
        if (R) __syncthreads();       // previous round's reads complete
        #pragma unroll
        for (int mh = 0; mh < 2; ++mh) {
            const int mi = R * 2 + mh;
            const int q2 = mh * 4 + kq;
            #pragma unroll
            for (int ni = 0; ni < 4; ++ni) {
                const int cc = ni * 16 + r;
                red[w][cc][q2 ^ (cc & 7)] = acc[mi][ni];
            }
        }
        __syncthreads();
        // reduce + epilogue: thread owns (col = tid&63, row-quad q2 = tid>>6)
        const int col = tid & 63;
        const int q2  = tid >> 6;
        const int swz = q2 ^ (col & 7);
        f32x4 s = red[0][col][swz];
        #pragma unroll
        for (int ww = 1; ww < 8; ++ww) s += red[ww][col][swz];
        const int gn = n0 + col;
        float bv = bias ? bias[gn] : 0.f;
        #pragma unroll
        for (int e = 0; e < 4; ++e) {
            const int gm = m0 + R * 32 + q2 * 4 + e;
            float v = s[e] + bv;
            if (ACT == 2) v = gelu_f(v);
            if (ACT == 3) v = (gn < fthr) ? fmap_f(v) : v;
            const size_t o = (size_t)gm * N + gn;
            if (PLANES) {
                unsigned short h = f2bf(v);
                Oh[o] = h;
                Ol[o] = f2bf(v - bf2f(h));
            } else {
                if (RES) v += Rsrc[o];
                C[o] = v;
            }
        }
    }
}

// ---------------- attention phase 1: per-chunk Mc = K^T V, ksum ----------------
__global__ __launch_bounds__(256) void attn_p1(
    const float* __restrict__ kbuf, const float* __restrict__ vbuf,
    float* __restrict__ Mc, float* __restrict__ ksum, int rs)
{
    const int h = blockIdx.x >> 5, c = blockIdx.x & 31;
    const int tid = threadIdx.x;
    const int tx = tid & 15, ty = tid >> 4;
    __shared__ float Ks[CHUNK][HD + 1];
    __shared__ float Vs[CHUNK][HD + 1];
    #pragma unroll
    for (int i = 0; i < 16; ++i) {
        int idx = tid + i * 256;           // 0..4095
        int t = idx >> 6, d = idx & 63;
        size_t g = (size_t)(c * CHUNK + t) * rs + h * HD + d;
        Ks[t][d] = kbuf[g];
        Vs[t][d] = vbuf[g];
    }
    __syncthreads();

    float acc[4][4] = {};
    for (int t = 0; t < CHUNK; ++t) {
        float ka[4], vb[4];
        #pragma unroll
        for (int i = 0; i < 4; ++i) ka[i] = Ks[t][ty * 4 + i];
        #pragma unroll
        for (int j = 0; j < 4; ++j) vb[j] = Vs[t][tx * 4 + j];
        #pragma unroll
        for (int i = 0; i < 4; ++i)
            #pragma unroll
            for (int j = 0; j < 4; ++j)
                acc[i][j] += ka[i] * vb[j];
    }
    const size_t base = (size_t)(h * NCHUNK + c) * HD * HD;
    #pragma unroll
    for (int i = 0; i < 4; ++i)
        #pragma unroll
        for (int j = 0; j < 4; ++j)
            Mc[base + (size_t)(ty * 4 + i) * HD + tx * 4 + j] = acc[i][j];

    if (tid < HD) {
        float s = 0.f;
        for (int t = 0; t < CHUNK; ++t) s += Ks[t][tid];
        ksum[(size_t)(h * NCHUNK + c) * HD + tid] = s;
    }
}

// ---------------- attention phase 2: exclusive prefix over chunks ----------------
// All 32 chunk values prefetched into registers (independent loads pipeline),
// then register prefix + stores.  (Fusing this into p3 REGRESSED — R11.)
__global__ __launch_bounds__(64) void attn_scan(
    float* __restrict__ Mc, float* __restrict__ ksum)
{
    const int b = blockIdx.x;        // 0 .. 8*65-1
    const int h = b / 65, p = b % 65;
    const int tid = threadIdx.x;     // 0..63
    float v[NCHUNK];
    if (p < HD) {
        const size_t base = ((size_t)(h * NCHUNK) * HD + p) * HD + tid;
        #pragma unroll
        for (int c = 0; c < NCHUNK; ++c)
            v[c] = Mc[base + (size_t)c * HD * HD];
        float run = 0.f;
        #pragma unroll
        for (int c = 0; c < NCHUNK; ++c) {
            Mc[base + (size_t)c * HD * HD] = run;
            run += v[c];
        }
    } else {
        const size_t base = (size_t)(h * NCHUNK) * HD + tid;
        #pragma unroll
        for (int c = 0; c < NCHUNK; ++c)
            v[c] = ksum[base + (size_t)c * HD];
        float run = 0.f;
        #pragma unroll
        for (int c = 0; c < NCHUNK; ++c) {
            ksum[base + (size_t)c * HD] = run;
            run += v[c];
        }
    }
}

// ---------------- attention phase 3: intra-chunk + state, normalize ----------------
// output: bf16 hi/lo planes of ao (consumed only by the O-projection GEMM)
__global__ __launch_bounds__(256) void attn_p3(
    const float* __restrict__ qbuf, const float* __restrict__ kbuf,
    const float* __restrict__ vbuf, const float* __restrict__ Mc,
    const float* __restrict__ ksum,
    unsigned short* __restrict__ aoh, unsigned short* __restrict__ aol, int rs)
{
    const int h = blockIdx.x >> 5, c = blockIdx.x & 31;
    const int tid = threadIdx.x;
    const int tx = tid & 15, ty = tid >> 4;
    __shared__ float Qs[CHUNK][HD + 1];
    __shared__ float Ks[CHUNK][HD + 1];
    __shared__ float Vs[CHUNK][HD + 1];
    __shared__ float Ss[CHUNK][CHUNK + 1];
    __shared__ float Ms[HD][HD + 1];
    __shared__ float kp[HD], den[CHUNK];

    const size_t mbase = (size_t)(h * NCHUNK + c) * HD * HD;
    #pragma unroll
    for (int i = 0; i < 16; ++i) {
        int idx = tid + i * 256;
        int t = idx >> 6, d = idx & 63;
        size_t g = (size_t)(c * CHUNK + t) * rs + h * HD + d;
        Qs[t][d] = qbuf[g];
        Ks[t][d] = kbuf[g];
        Vs[t][d] = vbuf[g];
        Ms[t][d] = Mc[mbase + (size_t)t * HD + d];
    }
    if (tid < HD) kp[tid] = ksum[(size_t)(h * NCHUNK + c) * HD + tid];
    __syncthreads();

    // S = Q K^T with causal mask (within chunk)
    {
        float acc[4][4] = {};
        for (int d = 0; d < HD; ++d) {
            float qa[4], kb[4];
            #pragma unroll
            for (int i = 0; i < 4; ++i) qa[i] = Qs[ty * 4 + i][d];
            #pragma unroll
            for (int j = 0; j < 4; ++j) kb[j] = Ks[tx * 4 + j][d];
            #pragma unroll
            for (int i = 0; i < 4; ++i)
                #pragma unroll
                for (int j = 0; j < 4; ++j)
                    acc[i][j] += qa[i] * kb[j];
        }
        #pragma unroll
        for (int i = 0; i < 4; ++i)
            #pragma unroll
            for (int j = 0; j < 4; ++j) {
                int t = ty * 4 + i, u = tx * 4 + j;
                Ss[t][u] = (u <= t) ? acc[i][j] : 0.f;
            }
    }
    __syncthreads();

    // den_t = 1e-6 + q_t . ksum_pre + rowsum(masked S)
    if (tid < CHUNK) {
        int t = tid;
        float s = 1e-6f;
        for (int d = 0; d < HD; ++d) s += Qs[t][d] * kp[d];
        for (int u = 0; u < CHUNK; ++u) s += Ss[t][u];
        den[t] = s;
    }
    __syncthreads();

    // out = (Q @ Mpre + S @ V) / den
    {
        float acc[4][4] = {};
        for (int d = 0; d < HD; ++d) {
            float qa[4], mb[4];
            #pragma unroll
            for (int i = 0; i < 4; ++i) qa[i] = Qs[ty * 4 + i][d];
            #pragma unroll
            for (int j = 0; j < 4; ++j) mb[j] = Ms[d][tx * 4 + j];
            #pragma unroll
            for (int i = 0; i < 4; ++i)
                #pragma unroll
                for (int j = 0; j < 4; ++j)
                    acc[i][j] += qa[i] * mb[j];
        }
        for (int u = 0; u < CHUNK; ++u) {
            float sa[4], vb[4];
            #pragma unroll
            for (int i = 0; i < 4; ++i) sa[i] = Ss[ty * 4 + i][u];
            #pragma unroll
            for (int j = 0; j < 4; ++j) vb[j] = Vs[u][tx * 4 + j];
            #pragma unroll
            for (int i = 0; i < 4; ++i)
                #pragma unroll
                for (int j = 0; j < 4; ++j)
                    acc[i][j] += sa[i] * vb[j];
        }
        #pragma unroll
        for (int i = 0; i < 4; ++i) {
            int t = ty * 4 + i;
            float inv = 1.f / den[t];
            #pragma unroll
            for (int j = 0; j < 4; ++j) {
                float vv = acc[i][j] * inv;
                unsigned short hh = f2bf(vv);
                size_t o = (size_t)(c * CHUNK + t) * DIM + h * HD + tx * 4 + j;
                aoh[o] = hh;
                aol[o] = f2bf(vv - bf2f(hh));
            }
        }
    }
}

// ---------------- host launch ----------------
extern "C" void kernel_launch(void* const* d_in, const int* in_sizes, int n_in,
                              void* d_out, int out_size, void* d_ws, size_t ws_size,
                              hipStream_t stream)
{
    const float* tok  = (const float*)d_in[0];
    const float* pos  = (const float*)d_in[1];
    const float* ln1w = (const float*)d_in[2];
    const float* ln1b = (const float*)d_in[3];
    const float* wq   = (const float*)d_in[4];
    const float* wk   = (const float*)d_in[5];
    const float* wv   = (const float*)d_in[6];
    const float* wo   = (const float*)d_in[7];
    const float* ln2w = (const float*)d_in[8];
    const float* ln2b = (const float*)d_in[9];
    const float* w1   = (const float*)d_in[10];
    const float* b1   = (const float*)d_in[11];
    const float* w2   = (const float*)d_in[12];
    const float* b2   = (const float*)d_in[13];
    const float* lnfw = (const float*)d_in[14];
    const float* lnfb = (const float*)d_in[15];
    const int*   ids  = (const int*)d_in[16];
    float* outp = (float*)d_out;

    typedef unsigned short us;
    char* p = (char*)d_ws;
    float* x   = (float*)p; p += (size_t)SD * 4;
    float* qkv = (float*)p; p += (size_t)SQL * 3 * DIM * 4;
    float* Mc  = (float*)p; p += (size_t)NHEADS * NCHUNK * HD * HD * 4;
    float* ksm = (float*)p; p += (size_t)NHEADS * NCHUNK * HD * 4;

    us* xnH = (us*)p; p += (size_t)SD * 2;
    us* xnL = (us*)p; p += (size_t)SD * 2;
    us* aoH = (us*)p; p += (size_t)SD * 2;
    us* aoL = (us*)p; p += (size_t)SD * 2;
    us* cinH = (us*)p; p += (size_t)SD * 2;
    us* cinL = (us*)p; p += (size_t)SD * 2;
    us* h1H = (us*)p; p += (size_t)SQL * HID * 2;
    us* h1L = (us*)p; p += (size_t)SQL * HID * 2;
    us* tokH = (us*)p; p += (size_t)VOC * DIM * 2;
    us* wqkvH = (us*)p; p += (size_t)NLAYERS * 3 * DD * 2;
    us* wqkvL = (us*)p; p += (size_t)NLAYERS * 3 * DD * 2;
    us* woH = (us*)p; p += (size_t)NLAYERS * DD * 2;
    us* woL = (us*)p; p += (size_t)NLAYERS * DD * 2;
    const size_t W1SZ = (size_t)NLAYERS * NLEVELS * DIM * HID;
    us* w1H = (us*)p; p += W1SZ * 2;
    us* w1L = (us*)p; p += W1SZ * 2;
    us* w2H = (us*)p; p += W1SZ * 2;
    us* w2L = (us*)p; p += W1SZ * 2;

    // ---- weight / embedding conversions (per call; memory-bound) ----
    {
        long long n4 = (long long)VOC * DIM / 4;
        conv_rh_k<<<(unsigned)((n4 + 255) / 256), 256, 0, stream>>>(tok, tokH, n4);
        dim3 gt(DIM / 32, DIM / 32, NLAYERS);
        conv_t_k<<<gt, 256, 0, stream>>>(wq, wqkvH,          wqkvL,          DIM, DIM, DD, (size_t)3 * DD);
        conv_t_k<<<gt, 256, 0, stream>>>(wk, wqkvH + DD,     wqkvL + DD,     DIM, DIM, DD, (size_t)3 * DD);
        conv_t_k<<<gt, 256, 0, stream>>>(wv, wqkvH + 2 * DD, wqkvL + 2 * DD, DIM, DIM, DD, (size_t)3 * DD);
        conv_t_k<<<gt, 256, 0, stream>>>(wo, woH, woL, DIM, DIM, DD, DD);
        dim3 g1(HID / 32, DIM / 32, NLAYERS * NLEVELS);
        conv_t_k<<<g1, 256, 0, stream>>>(w1, w1H, w1L, DIM, HID,
                                         (size_t)DIM * HID, (size_t)DIM * HID);
        dim3 g2(DIM / 32, HID / 32, NLAYERS * NLEVELS);
        conv_t_k<<<g2, 256, 0, stream>>>(w2, w2H, w2L, HID, DIM,
                                         (size_t)DIM * HID, (size_t)DIM * HID);
    }

    embed_k<<<SD / 256, 256, 0, stream>>>(tok, pos, ids, x);

    const dim3 gqkv(3 * DIM / 64, SQL / 128);      // (24, 16)  BN=64
    const dim3 g512(DIM / 64, SQL / 64);           // (8, 32)   [split-K kernel]
    const dim3 gw1(HID / 64, SQL / 128);           // (32, 16)  BN=64
    const dim3 ghead(SQL / 128, (VOC + 127) / 128);// (16, 393) M-fastest, BN=128
    const int RS = 3 * DIM;

    for (int l = 0; l < NLAYERS; ++l) {
        // --- attention block ---
        ln_k<<<SQL, 256, 0, stream>>>(x, xnH, xnL, ln1w + l * DIM, ln1b + l * DIM);
        // fused QKV: N = 1536, fmap on cols < 1024 (q,k)
        gemm_t<3, false, false, false, true, false, 64><<<gqkv, 256, 0, stream>>>(
            xnH, xnL, wqkvH + (size_t)l * 3 * DD, wqkvL + (size_t)l * 3 * DD,
            nullptr, nullptr, qkv, nullptr, nullptr, SQL, 3 * DIM, DIM, 2 * DIM);
        attn_p1<<<NHEADS * NCHUNK, 256, 0, stream>>>(qkv + DIM, qkv + 2 * DIM, Mc, ksm, RS);
        attn_scan<<<NHEADS * 65, 64, 0, stream>>>(Mc, ksm);
        attn_p3<<<NHEADS * NCHUNK, 256, 0, stream>>>(
            qkv, qkv + DIM, qkv + 2 * DIM, Mc, ksm, aoH, aoL, RS);
        // x += ao @ wo
        gemm_ks<0, true, false><<<g512, 512, 0, stream>>>(
            aoH, aoL, woH + (size_t)l * DD, woL + (size_t)l * DD,
            nullptr, x, x, nullptr, nullptr, SQL, DIM, DIM, 0);

        // --- CMS block ---
        ln_k<<<SQL, 256, 0, stream>>>(x, xnH, xnL, ln2w + l * DIM, ln2b + l * DIM);
        const us* cH = xnH; const us* cL = xnL;
        for (int lvl = 0; lvl < NLEVELS; ++lvl) {
            const size_t off1 = (size_t)(l * NLEVELS + lvl) * DIM * HID;
            const float* b1p = b1 + (size_t)(l * NLEVELS + lvl) * HID;
            const float* b2p = b2 + (size_t)(l * NLEVELS + lvl) * DIM;
            gemm_t<2, false, true, false, true, false, 64><<<gw1, 256, 0, stream>>>(
                cH, cL, w1H + off1, w1L + off1, b1p, nullptr,
                nullptr, h1H, h1L, SQL, HID, DIM, 0);
            if (lvl < NLEVELS - 1) {
                gemm_ks<0, false, true><<<g512, 512, 0, stream>>>(
                    h1H, h1L, w2H + off1, w2L + off1, b2p, nullptr,
                    nullptr, cinH, cinL, SQL, DIM, HID, 0);
                cH = cinH; cL = cinL;
            } else {
                // fuse residual: x += level_out
                gemm_ks<0, true, false><<<g512, 512, 0, stream>>>(
                    h1H, h1L, w2H + off1, w2L + off1, b2p, x,
                    x, nullptr, nullptr, SQL, DIM, HID, 0);
            }
        }
    }

    // --- final LN + tied head ---
    ln_k<<<SQL, 256, 0, stream>>>(x, xnH, xnL, lnfw, lnfb);
    // head: bf16x2 (drop a*lo_b term), BN=128, M-fastest grid (no XCD swizzle)
    gemm_t<0, false, false, true, false, true, 128><<<ghead, 256, 0, stream>>>(
        xnH, xnL, tokH, nullptr, nullptr, nullptr,
        outp, nullptr, nullptr, SQL, VOC, DIM, 0);
}

// Round 14
// 1807.633 us; speedup vs baseline: 1.0177x; 1.0177x over previous
//
#include <hip/hip_runtime.h>

// ---------------- constants ----------------
#define SQL 2048      // sequence length
#define DIM 512
#define NHEADS 8
#define HD 64         // head dim
#define NLAYERS 4
#define NLEVELS 3
#define HID 2048
#define VOC 50257
#define CHUNK 64
#define NCHUNK 32     // SQL / CHUNK
#define SD (SQL * DIM)
#define DD (DIM * DIM)

typedef __attribute__((ext_vector_type(8))) short bf16x8;   // 8 bf16 = 4 VGPR
typedef __attribute__((ext_vector_type(4))) float f32x4;    // MFMA accumulator

__device__ __forceinline__ float gelu_f(float x) {
    float x3 = x * x * x;
    return 0.5f * x * (1.f + tanhf(0.7978845608028654f * (x + 0.044715f * x3)));
}
// fmap = elu(x)+1 : x>0 ? x+1 : exp(x)
__device__ __forceinline__ float fmap_f(float x) {
    return x > 0.f ? x + 1.f : expf(x);
}
// fp32 -> bf16 round-to-nearest-even
__device__ __forceinline__ unsigned short f2bf(float x) {
    unsigned int u = __float_as_uint(x);
    u = (u + 0x7fffu + ((u >> 16) & 1u)) >> 16;
    return (unsigned short)u;
}
__device__ __forceinline__ float bf2f(unsigned short h) {
    return __uint_as_float(((unsigned int)h) << 16);
}

// ---------------- embedding ----------------
__global__ __launch_bounds__(256) void embed_k(
    const float* __restrict__ tok, const float* __restrict__ pos,
    const int* __restrict__ ids, float* __restrict__ x)
{
    int idx = blockIdx.x * 256 + threadIdx.x;       // 0 .. S*D-1
    int t = idx >> 9;                               // idx / 512
    int d = idx & 511;
    x[idx] = tok[(size_t)ids[t] * DIM + d] + pos[idx];
}

// ---------------- layernorm: fp32 in -> bf16 hi/lo planes out ----------------
__global__ __launch_bounds__(256) void ln_k(
    const float* __restrict__ in, unsigned short* __restrict__ oh,
    unsigned short* __restrict__ ol,
    const float* __restrict__ w, const float* __restrict__ b)
{
    int t = blockIdx.x, tid = threadIdx.x;
    float v0 = in[t * DIM + tid];
    float v1 = in[t * DIM + 256 + tid];
    float s = v0 + v1, sq = v0 * v0 + v1 * v1;
    #pragma unroll
    for (int off = 32; off > 0; off >>= 1) {
        s  += __shfl_down(s, off);
        sq += __shfl_down(sq, off);
    }
    __shared__ float ss[4], sqs[4];
    int wave = tid >> 6, lane = tid & 63;
    if (lane == 0) { ss[wave] = s; sqs[wave] = sq; }
    __syncthreads();
    float S  = ss[0] + ss[1] + ss[2] + ss[3];
    float SQ = sqs[0] + sqs[1] + sqs[2] + sqs[3];
    float m   = S * (1.f / DIM);
    float var = SQ * (1.f / DIM) - m * m;
    float rs  = rsqrtf(var + 1e-5f);
    float y0 = (v0 - m) * rs * w[tid]       + b[tid];
    float y1 = (v1 - m) * rs * w[256 + tid] + b[256 + tid];
    unsigned short h0 = f2bf(y0), h1 = f2bf(y1);
    oh[t * DIM + tid]       = h0;
    ol[t * DIM + tid]       = f2bf(y0 - bf2f(h0));
    oh[t * DIM + 256 + tid] = h1;
    ol[t * DIM + 256 + tid] = f2bf(y1 - bf2f(h1));
}

// ---------------- convert rows, hi plane only: fp32 -> bf16 ----------------
__global__ __launch_bounds__(256) void conv_rh_k(
    const float* __restrict__ in, unsigned short* __restrict__ oh, long long n4)
{
    long long i = (long long)blockIdx.x * 256 + threadIdx.x;
    if (i >= n4) return;
    float4 v = ((const float4*)in)[i];
    ushort4 hh;
    hh.x = f2bf(v.x); hh.y = f2bf(v.y); hh.z = f2bf(v.z); hh.w = f2bf(v.w);
    ((ushort4*)oh)[i] = hh;
}

// ---------------- convert + transpose: fp32 [K][N] -> bf16 hi/lo [N][K] ----------------
// grid: (N/32, K/32, nmat), 256 threads.  srcZ/dstZ: per-z element strides.
__global__ __launch_bounds__(256) void conv_t_k(
    const float* __restrict__ in, unsigned short* __restrict__ oh,
    unsigned short* __restrict__ ol, int K, int N,
    size_t srcZ, size_t dstZ)
{
    in += (size_t)blockIdx.z * srcZ;
    oh += (size_t)blockIdx.z * dstZ;
    ol += (size_t)blockIdx.z * dstZ;
    __shared__ float T[32][33];
    const int n0 = blockIdx.x * 32, k0 = blockIdx.y * 32;
    const int tr = threadIdx.x >> 3, tc = threadIdx.x & 7;   // 32 rows x 8 col-groups
    float4 v = *(const float4*)(in + (size_t)(k0 + tr) * N + n0 + tc * 4);
    T[tr][tc * 4 + 0] = v.x;
    T[tr][tc * 4 + 1] = v.y;
    T[tr][tc * 4 + 2] = v.z;
    T[tr][tc * 4 + 3] = v.w;
    __syncthreads();
    float o0 = T[tc * 4 + 0][tr];
    float o1 = T[tc * 4 + 1][tr];
    float o2 = T[tc * 4 + 2][tr];
    float o3 = T[tc * 4 + 3][tr];
    unsigned short h0 = f2bf(o0), h1 = f2bf(o1), h2 = f2bf(o2), h3 = f2bf(o3);
    ushort4 hh; hh.x = h0; hh.y = h1; hh.z = h2; hh.w = h3;
    ushort4 ll;
    ll.x = f2bf(o0 - bf2f(h0));
    ll.y = f2bf(o1 - bf2f(h1));
    ll.z = f2bf(o2 - bf2f(h2));
    ll.w = f2bf(o3 - bf2f(h3));
    size_t off = (size_t)(n0 + tr) * K + k0 + tc * 4;
    *(ushort4*)(oh + off) = hh;
    *(ushort4*)(ol + off) = ll;
}

// ============ MFMA GEMM (tiled): 128xBN block, 4 waves, LDS-staged ============
// A planes [M][K], B planes [N][K], k-major bf16 hi/lo.  BM=128, BK=32.
// BN = 128 (wave-tile 64x64) or 64 (wave-tile 64x32, doubles grid for mid GEMMs).
// Reg-staged copy w/ prefetch + T2 chunk-XOR swizzle (R12: conflicts 1.9e7 -> 0,
// head 266->259).  FINAL-STATE NOTES (failed-experiment ledger):
//   R7  gload_lds + LDS dbuf + 1 barrier  -> neutral (TLP already hides drain)
//   R9  BN=256 head                       -> regressed (occupancy 32->11%)
//   R9  LN fused into GEMM prologue       -> regressed (per-N-block stats redo)
//   R10 XCD-aware block swizzle           -> regressed (FETCH 220->355 MB)
//   R11 scan fused into attn_p3           -> regressed (serial L2 prefix)
//   R13 counted-waitcnt barriers (T4-lite)-> neutral  (barrier drain not the stall)
// Bound analysis (R13): kernel is LDS-BANDWIDTH-bound; measured MfmaUtil 36.5%
// vs ~41% model ceiling for this layout (48KB rd + 24KB wr per block-k-step).
// Past this requires the 8-phase/256^2 template (multi-round race-screen).
// X3: include a_lo*b_hi AND a_hi*b_lo (X3=false drops b_lo: 2 MFMAs, no Bl).
// ACT: 0 none, 2 gelu, 3 fmap if (col < fthr).  NG: guard N tail.
// MSWAP: blockIdx.x = M-tile (M-fastest launch order -> B-tile shared in L2).
template<int ACT, bool RES, bool PLANES, bool NG, bool X3, bool MSWAP, int BN>
__global__ __launch_bounds__(256) void gemm_t(
    const unsigned short* __restrict__ Ah, const unsigned short* __restrict__ Al,
    const unsigned short* __restrict__ Bh, const unsigned short* __restrict__ Bl,
    const float* __restrict__ bias, const float* __restrict__ Rsrc,
    float* __restrict__ C, unsigned short* __restrict__ Oh,
    unsigned short* __restrict__ Ol,
    int M, int N, int K, int fthr)
{
    constexpr int NW = BN / 2;      // wave-tile N width (64 or 32)
    constexpr int NF = NW / 16;     // B fragments per wave (4 or 2)
    __shared__ unsigned short sAh[4096], sAl[4096];
    __shared__ unsigned short sBh[BN * 32];
    __shared__ unsigned short sBl[X3 ? BN * 32 : 64];

    const int tid  = threadIdx.x;
    const int w    = tid >> 6, lane = tid & 63;
    const int r    = lane & 15, kq = lane >> 4;
    const int wr   = w >> 1, wc = w & 1;          // 2x2 wave grid
    const int m0   = (MSWAP ? blockIdx.x : blockIdx.y) * 128;
    const int n0   = (MSWAP ? blockIdx.y : blockIdx.x) * BN;

    // staging: A has 512 slots (2/thread: tid, tid+256); B has BN*4 slots.
    const int srow = tid >> 2;          // 0..63
    const int sch  = tid & 3;           // 16B chunk within 64B row
    const int ar0 = m0 + srow, ar1 = ar0 + 64;
    int br0 = n0 + srow;
    if (NG) br0 = br0 < N ? br0 : N - 1;
    const unsigned short* pAh0 = Ah + (size_t)ar0 * K + sch * 8;
    const unsigned short* pAh1 = Ah + (size_t)ar1 * K + sch * 8;
    const unsigned short* pAl0 = Al + (size_t)ar0 * K + sch * 8;
    const unsigned short* pAl1 = Al + (size_t)ar1 * K + sch * 8;
    const unsigned short* pBh0 = Bh + (size_t)br0 * K + sch * 8;
    const unsigned short* pBl0 = X3 ? Bl + (size_t)br0 * K + sch * 8 : nullptr;
    const unsigned short* pBh1 = nullptr;
    const unsigned short* pBl1 = nullptr;
    if constexpr (BN == 128) {
        int br1 = n0 + 64 + srow;
        if (NG) br1 = br1 < N ? br1 : N - 1;
        pBh1 = Bh + (size_t)br1 * K + sch * 8;
        if constexpr (X3) pBl1 = Bl + (size_t)br1 * K + sch * 8;
    }

    // prologue loads (k-step 0)
    bf16x8 rAh0 = *(const bf16x8*)pAh0, rAh1 = *(const bf16x8*)pAh1;
    bf16x8 rAl0 = *(const bf16x8*)pAl0, rAl1 = *(const bf16x8*)pAl1;
    bf16x8 rBh0 = *(const bf16x8*)pBh0;
    bf16x8 rBh1{}, rBl0{}, rBl1{};
    if constexpr (X3) rBl0 = *(const bf16x8*)pBl0;
    if constexpr (BN == 128) {
        rBh1 = *(const bf16x8*)pBh1;
        if constexpr (X3) rBl1 = *(const bf16x8*)pBl1;
    }

    f32x4 acc[4][NF] = {};
    // T2 swizzle: chunk' = chunk ^ ((row>>1)&3).  Row+64 keeps the same key,
    // so the upper-half (+2048 elems) write reuses sw.
    const int sw = srow * 32 + ((sch ^ ((srow >> 1) & 3)) * 8);
    const int kx = (kq ^ ((r >> 1) & 3)) * 8;     // read-side swizzled chunk

    for (int ks = 0; ks < K; ks += 32) {
        __syncthreads();                 // prev iter's ds_reads done
        *(bf16x8*)&sAh[sw] = rAh0;  *(bf16x8*)&sAh[sw + 2048] = rAh1;
        *(bf16x8*)&sAl[sw] = rAl0;  *(bf16x8*)&sAl[sw + 2048] = rAl1;
        *(bf16x8*)&sBh[sw] = rBh0;
        if constexpr (BN == 128) *(bf16x8*)&sBh[sw + 2048] = rBh1;
        if constexpr (X3) {
            *(bf16x8*)&sBl[sw] = rBl0;
            if constexpr (BN == 128) *(bf16x8*)&sBl[sw + 2048] = rBl1;
        }
        __syncthreads();                 // tiles visible

        if (ks + 32 < K) {               // prefetch next k-step (hides under MFMA)
            pAh0 += 32; pAh1 += 32; pAl0 += 32; pAl1 += 32;
            pBh0 += 32;
            rAh0 = *(const bf16x8*)pAh0; rAh1 = *(const bf16x8*)pAh1;
            rAl0 = *(const bf16x8*)pAl0; rAl1 = *(const bf16x8*)pAl1;
            rBh0 = *(const bf16x8*)pBh0;
            if constexpr (X3) { pBl0 += 32; rBl0 = *(const bf16x8*)pBl0; }
            if constexpr (BN == 128) {
                pBh1 += 32; rBh1 = *(const bf16x8*)pBh1;
                if constexpr (X3) { pBl1 += 32; rBl1 = *(const bf16x8*)pBl1; }
            }
        }

        bf16x8 a_h[4], a_l[4];
        #pragma unroll
        for (int mi = 0; mi < 4; ++mi) {
            const int off = (wr * 64 + mi * 16 + r) * 32 + kx;
            a_h[mi] = *(const bf16x8*)&sAh[off];
            a_l[mi] = *(const bf16x8*)&sAl[off];
        }
        #pragma unroll
        for (int ni = 0; ni < NF; ++ni) {
            const int off = (wc * NW + ni * 16 + r) * 32 + kx;
            const bf16x8 b_h = *(const bf16x8*)&sBh[off];
            #pragma unroll
            for (int mi = 0; mi < 4; ++mi) {
                acc[mi][ni] = __builtin_amdgcn_mfma_f32_16x16x32_bf16(
                    a_h[mi], b_h, acc[mi][ni], 0, 0, 0);
                acc[mi][ni] = __builtin_amdgcn_mfma_f32_16x16x32_bf16(
                    a_l[mi], b_h, acc[mi][ni], 0, 0, 0);
            }
            if constexpr (X3) {
                const bf16x8 b_l = *(const bf16x8*)&sBl[off];
                #pragma unroll
                for (int mi = 0; mi < 4; ++mi)
                    acc[mi][ni] = __builtin_amdgcn_mfma_f32_16x16x32_bf16(
                        a_h[mi], b_l, acc[mi][ni], 0, 0, 0);
            }
        }
    }

    // epilogue: C/D layout col = lane&15, row = (lane>>4)*4 + reg  [m89-verified]
    #pragma unroll
    for (int mi = 0; mi < 4; ++mi)
        #pragma unroll
        for (int ni = 0; ni < NF; ++ni) {
            const int nn = n0 + wc * NW + ni * 16 + r;
            if (NG && nn >= N) continue;
            #pragma unroll
            for (int g = 0; g < 4; ++g) {
                const int mm = m0 + wr * 64 + mi * 16 + kq * 4 + g;
                float v = acc[mi][ni][g];
                if (bias) v += bias[nn];
                if (ACT == 2) v = gelu_f(v);
                if (ACT == 3) v = (nn < fthr) ? fmap_f(v) : v;
                const size_t o = (size_t)mm * N + nn;
                if (PLANES) {
                    unsigned short h = f2bf(v);
                    Oh[o] = h;
                    Ol[o] = f2bf(v - bf2f(h));
                } else {
                    if (RES) v += Rsrc[o];
                    C[o] = v;
                }
            }
        }
}

// ============ MFMA GEMM (split-K): 8 waves split K 8-way, LDS reduce ============
// Block = 512 thr = 8 waves (2 waves/SIMD TLP hides reg-direct load latency).
// Requires M%64==0, N%64==0, K%256==0.
// ACT: 0 none, 2 gelu, 3 fmap if (col < fthr).
template<int ACT, bool RES, bool PLANES>
__global__ __launch_bounds__(512) void gemm_ks(
    const unsigned short* __restrict__ Ah, const unsigned short* __restrict__ Al,
    const unsigned short* __restrict__ Bh, const unsigned short* __restrict__ Bl,
    const float* __restrict__ bias, const float* __restrict__ Rsrc,
    float* __restrict__ C, unsigned short* __restrict__ Oh,
    unsigned short* __restrict__ Ol,
    int M, int N, int K, int fthr)
{
    const int tid  = threadIdx.x;
    const int w    = tid >> 6;     // wave 0..7 = K-eighth owner
    const int lane = tid & 63;
    const int r  = lane & 15;
    const int kq = lane >> 4;
    const int m0 = blockIdx.y * 64, n0 = blockIdx.x * 64;
    const int Kw = K >> 3;

    f32x4 acc[4][4] = {};

    size_t aoff[4], boff[4];
    #pragma unroll
    for (int i = 0; i < 4; ++i) {
        aoff[i] = (size_t)(m0 + i * 16 + r) * K + w * Kw + kq * 8;
        boff[i] = (size_t)(n0 + i * 16 + r) * K + w * Kw + kq * 8;
    }

    for (int k0 = 0; k0 < Kw; k0 += 32) {
        bf16x8 ah[4], al4[4], bh[4], bl4[4];
        #pragma unroll
        for (int i = 0; i < 4; ++i) {
            ah[i]  = *(const bf16x8*)(Ah + aoff[i] + k0);
            al4[i] = *(const bf16x8*)(Al + aoff[i] + k0);
            bh[i]  = *(const bf16x8*)(Bh + boff[i] + k0);
            bl4[i] = *(const bf16x8*)(Bl + boff[i] + k0);
        }
        #pragma unroll
        for (int mi = 0; mi < 4; ++mi)
            #pragma unroll
            for (int ni = 0; ni < 4; ++ni) {
                acc[mi][ni] = __builtin_amdgcn_mfma_f32_16x16x32_bf16(
                    ah[mi], bh[ni], acc[mi][ni], 0, 0, 0);
                acc[mi][ni] = __builtin_amdgcn_mfma_f32_16x16x32_bf16(
                    ah[mi], bl4[ni], acc[mi][ni], 0, 0, 0);
                acc[mi][ni] = __builtin_amdgcn_mfma_f32_16x16x32_bf16(
                    al4[mi], bh[ni], acc[mi][ni], 0, 0, 0);
            }
    }

    // ---- cross-wave reduction: two 32-row rounds, XOR-swizzled f32x4 LDS ----
    __shared__ f32x4 red[8][64][8];   // 64 KB

    #pragma unroll
    for (int R = 0; R < 2; ++R) {
        if (R) __syncthreads();       // previous round's reads complete
        #pragma unroll
        for (int mh = 0; mh < 2; ++mh) {
            const int mi = R * 2 + mh;
            const int q2 = mh * 4 + kq;
            #pragma unroll
            for (int ni = 0; ni < 4; ++ni) {
                const int cc = ni * 16 + r;
                red[w][cc][q2 ^ (cc & 7)] = acc[mi][ni];
            }
        }
        __syncthreads();
        // reduce + epilogue: thread owns (col = tid&63, row-quad q2 = tid>>6)
        const int col = tid & 63;
        const int q2  = tid >> 6;
        const int swz = q2 ^ (col & 7);
        f32x4 s = red[0][col][swz];
        #pragma unroll
        for (int ww = 1; ww < 8; ++ww) s += red[ww][col][swz];
        const int gn = n0 + col;
        float bv = bias ? bias[gn] : 0.f;
        #pragma unroll
        for (int e = 0; e < 4; ++e) {
            const int gm = m0 + R * 32 + q2 * 4 + e;
            float v = s[e] + bv;
            if (ACT == 2) v = gelu_f(v);
            if (ACT == 3) v = (gn < fthr) ? fmap_f(v) : v;
            const size_t o = (size_t)gm * N + gn;
            if (PLANES) {
                unsigned short h = f2bf(v);
                Oh[o] = h;
                Ol[o] = f2bf(v - bf2f(h));
            } else {
                if (RES) v += Rsrc[o];
                C[o] = v;
            }
        }
    }
}

// ---------------- attention phase 1: per-chunk Mc = K^T V, ksum ----------------
__global__ __launch_bounds__(256) void attn_p1(
    const float* __restrict__ kbuf, const float* __restrict__ vbuf,
    float* __restrict__ Mc, float* __restrict__ ksum, int rs)
{
    const int h = blockIdx.x >> 5, c = blockIdx.x & 31;
    const int tid = threadIdx.x;
    const int tx = tid & 15, ty = tid >> 4;
    __shared__ float Ks[CHUNK][HD + 1];
    __shared__ float Vs[CHUNK][HD + 1];
    #pragma unroll
    for (int i = 0; i < 16; ++i) {
        int idx = tid + i * 256;           // 0..4095
        int t = idx >> 6, d = idx & 63;
        size_t g = (size_t)(c * CHUNK + t) * rs + h * HD + d;
        Ks[t][d] = kbuf[g];
        Vs[t][d] = vbuf[g];
    }
    __syncthreads();

    float acc[4][4] = {};
    for (int t = 0; t < CHUNK; ++t) {
        float ka[4], vb[4];
        #pragma unroll
        for (int i = 0; i < 4; ++i) ka[i] = Ks[t][ty * 4 + i];
        #pragma unroll
        for (int j = 0; j < 4; ++j) vb[j] = Vs[t][tx * 4 + j];
        #pragma unroll
        for (int i = 0; i < 4; ++i)
            #pragma unroll
            for (int j = 0; j < 4; ++j)
                acc[i][j] += ka[i] * vb[j];
    }
    const size_t base = (size_t)(h * NCHUNK + c) * HD * HD;
    #pragma unroll
    for (int i = 0; i < 4; ++i)
        #pragma unroll
        for (int j = 0; j < 4; ++j)
            Mc[base + (size_t)(ty * 4 + i) * HD + tx * 4 + j] = acc[i][j];

    if (tid < HD) {
        float s = 0.f;
        for (int t = 0; t < CHUNK; ++t) s += Ks[t][tid];
        ksum[(size_t)(h * NCHUNK + c) * HD + tid] = s;
    }
}

// ---------------- attention phase 2: exclusive prefix over chunks ----------------
// All 32 chunk values prefetched into registers (independent loads pipeline),
// then register prefix + stores.  (Fusing this into p3 REGRESSED — R11.)
__global__ __launch_bounds__(64) void attn_scan(
    float* __restrict__ Mc, float* __restrict__ ksum)
{
    const int b = blockIdx.x;        // 0 .. 8*65-1
    const int h = b / 65, p = b % 65;
    const int tid = threadIdx.x;     // 0..63
    float v[NCHUNK];
    if (p < HD) {
        const size_t base = ((size_t)(h * NCHUNK) * HD + p) * HD + tid;
        #pragma unroll
        for (int c = 0; c < NCHUNK; ++c)
            v[c] = Mc[base + (size_t)c * HD * HD];
        float run = 0.f;
        #pragma unroll
        for (int c = 0; c < NCHUNK; ++c) {
            Mc[base + (size_t)c * HD * HD] = run;
            run += v[c];
        }
    } else {
        const size_t base = (size_t)(h * NCHUNK) * HD + tid;
        #pragma unroll
        for (int c = 0; c < NCHUNK; ++c)
            v[c] = ksum[base + (size_t)c * HD];
        float run = 0.f;
        #pragma unroll
        for (int c = 0; c < NCHUNK; ++c) {
            ksum[base + (size_t)c * HD] = run;
            run += v[c];
        }
    }
}

// ---------------- attention phase 3: intra-chunk + state, normalize ----------------
// output: bf16 hi/lo planes of ao (consumed only by the O-projection GEMM)
__global__ __launch_bounds__(256) void attn_p3(
    const float* __restrict__ qbuf, const float* __restrict__ kbuf,
    const float* __restrict__ vbuf, const float* __restrict__ Mc,
    const float* __restrict__ ksum,
    unsigned short* __restrict__ aoh, unsigned short* __restrict__ aol, int rs)
{
    const int h = blockIdx.x >> 5, c = blockIdx.x & 31;
    const int tid = threadIdx.x;
    const int tx = tid & 15, ty = tid >> 4;
    __shared__ float Qs[CHUNK][HD + 1];
    __shared__ float Ks[CHUNK][HD + 1];
    __shared__ float Vs[CHUNK][HD + 1];
    __shared__ float Ss[CHUNK][CHUNK + 1];
    __shared__ float Ms[HD][HD + 1];
    __shared__ float kp[HD], den[CHUNK];

    const size_t mbase = (size_t)(h * NCHUNK + c) * HD * HD;
    #pragma unroll
    for (int i = 0; i < 16; ++i) {
        int idx = tid + i * 256;
        int t = idx >> 6, d = idx & 63;
        size_t g = (size_t)(c * CHUNK + t) * rs + h * HD + d;
        Qs[t][d] = qbuf[g];
        Ks[t][d] = kbuf[g];
        Vs[t][d] = vbuf[g];
        Ms[t][d] = Mc[mbase + (size_t)t * HD + d];
    }
    if (tid < HD) kp[tid] = ksum[(size_t)(h * NCHUNK + c) * HD + tid];
    __syncthreads();

    // S = Q K^T with causal mask (within chunk)
    {
        float acc[4][4] = {};
        for (int d = 0; d < HD; ++d) {
            float qa[4], kb[4];
            #pragma unroll
            for (int i = 0; i < 4; ++i) qa[i] = Qs[ty * 4 + i][d];
            #pragma unroll
            for (int j = 0; j < 4; ++j) kb[j] = Ks[tx * 4 + j][d];
            #pragma unroll
            for (int i = 0; i < 4; ++i)
                #pragma unroll
                for (int j = 0; j < 4; ++j)
                    acc[i][j] += qa[i] * kb[j];
        }
        #pragma unroll
        for (int i = 0; i < 4; ++i)
            #pragma unroll
            for (int j = 0; j < 4; ++j) {
                int t = ty * 4 + i, u = tx * 4 + j;
                Ss[t][u] = (u <= t) ? acc[i][j] : 0.f;
            }
    }
    __syncthreads();

    // den_t = 1e-6 + q_t . ksum_pre + rowsum(masked S)
    if (tid < CHUNK) {
        int t = tid;
        float s = 1e-6f;
        for (int d = 0; d < HD; ++d) s += Qs[t][d] * kp[d];
        for (int u = 0; u < CHUNK; ++u) s += Ss[t][u];
        den[t] = s;
    }
    __syncthreads();

    // out = (Q @ Mpre + S @ V) / den
    {
        float acc[4][4] = {};
        for (int d = 0; d < HD; ++d) {
            float qa[4], mb[4];
            #pragma unroll
            for (int i = 0; i < 4; ++i) qa[i] = Qs[ty * 4 + i][d];
            #pragma unroll
            for (int j = 0; j < 4; ++j) mb[j] = Ms[d][tx * 4 + j];
            #pragma unroll
            for (int i = 0; i < 4; ++i)
                #pragma unroll
                for (int j = 0; j < 4; ++j)
                    acc[i][j] += qa[i] * mb[j];
        }
        for (int u = 0; u < CHUNK; ++u) {
            float sa[4], vb[4];
            #pragma unroll
            for (int i = 0; i < 4; ++i) sa[i] = Ss[ty * 4 + i][u];
            #pragma unroll
            for (int j = 0; j < 4; ++j) vb[j] = Vs[u][tx * 4 + j];
            #pragma unroll
            for (int i = 0; i < 4; ++i)
                #pragma unroll
                for (int j = 0; j < 4; ++j)
                    acc[i][j] += sa[i] * vb[j];
        }
        #pragma unroll
        for (int i = 0; i < 4; ++i) {
            int t = ty * 4 + i;
            float inv = 1.f / den[t];
            #pragma unroll
            for (int j = 0; j < 4; ++j) {
                float vv = acc[i][j] * inv;
                unsigned short hh = f2bf(vv);
                size_t o = (size_t)(c * CHUNK + t) * DIM + h * HD + tx * 4 + j;
                aoh[o] = hh;
                aol[o] = f2bf(vv - bf2f(hh));
            }
        }
    }
}

// ---------------- host launch ----------------
extern "C" void kernel_launch(void* const* d_in, const int* in_sizes, int n_in,
                              void* d_out, int out_size, void* d_ws, size_t ws_size,
                              hipStream_t stream)
{
    const float* tok  = (const float*)d_in[0];
    const float* pos  = (const float*)d_in[1];
    const float* ln1w = (const float*)d_in[2];
    const float* ln1b = (const float*)d_in[3];
    const float* wq   = (const float*)d_in[4];
    const float* wk   = (const float*)d_in[5];
    const float* wv   = (const float*)d_in[6];
    const float* wo   = (const float*)d_in[7];
    const float* ln2w = (const float*)d_in[8];
    const float* ln2b = (const float*)d_in[9];
    const float* w1   = (const float*)d_in[10];
    const float* b1   = (const float*)d_in[11];
    const float* w2   = (const float*)d_in[12];
    const float* b2   = (const float*)d_in[13];
    const float* lnfw = (const float*)d_in[14];
    const float* lnfb = (const float*)d_in[15];
    const int*   ids  = (const int*)d_in[16];
    float* outp = (float*)d_out;

    typedef unsigned short us;
    char* p = (char*)d_ws;
    float* x   = (float*)p; p += (size_t)SD * 4;
    float* qkv = (float*)p; p += (size_t)SQL * 3 * DIM * 4;
    float* Mc  = (float*)p; p += (size_t)NHEADS * NCHUNK * HD * HD * 4;
    float* ksm = (float*)p; p += (size_t)NHEADS * NCHUNK * HD * 4;

    us* xnH = (us*)p; p += (size_t)SD * 2;
    us* xnL = (us*)p; p += (size_t)SD * 2;
    us* aoH = (us*)p; p += (size_t)SD * 2;
    us* aoL = (us*)p; p += (size_t)SD * 2;
    us* cinH = (us*)p; p += (size_t)SD * 2;
    us* cinL = (us*)p; p += (size_t)SD * 2;
    us* h1H = (us*)p; p += (size_t)SQL * HID * 2;
    us* h1L = (us*)p; p += (size_t)SQL * HID * 2;
    us* tokH = (us*)p; p += (size_t)VOC * DIM * 2;
    us* wqkvH = (us*)p; p += (size_t)NLAYERS * 3 * DD * 2;
    us* wqkvL = (us*)p; p += (size_t)NLAYERS * 3 * DD * 2;
    us* woH = (us*)p; p += (size_t)NLAYERS * DD * 2;
    us* woL = (us*)p; p += (size_t)NLAYERS * DD * 2;
    const size_t W1SZ = (size_t)NLAYERS * NLEVELS * DIM * HID;
    us* w1H = (us*)p; p += W1SZ * 2;
    us* w1L = (us*)p; p += W1SZ * 2;
    us* w2H = (us*)p; p += W1SZ * 2;
    us* w2L = (us*)p; p += W1SZ * 2;

    // ---- weight / embedding conversions (per call; memory-bound) ----
    {
        long long n4 = (long long)VOC * DIM / 4;
        conv_rh_k<<<(unsigned)((n4 + 255) / 256), 256, 0, stream>>>(tok, tokH, n4);
        dim3 gt(DIM / 32, DIM / 32, NLAYERS);
        conv_t_k<<<gt, 256, 0, stream>>>(wq, wqkvH,          wqkvL,          DIM, DIM, DD, (size_t)3 * DD);
        conv_t_k<<<gt, 256, 0, stream>>>(wk, wqkvH + DD,     wqkvL + DD,     DIM, DIM, DD, (size_t)3 * DD);
        conv_t_k<<<gt, 256, 0, stream>>>(wv, wqkvH + 2 * DD, wqkvL + 2 * DD, DIM, DIM, DD, (size_t)3 * DD);
        conv_t_k<<<gt, 256, 0, stream>>>(wo, woH, woL, DIM, DIM, DD, DD);
        dim3 g1(HID / 32, DIM / 32, NLAYERS * NLEVELS);
        conv_t_k<<<g1, 256, 0, stream>>>(w1, w1H, w1L, DIM, HID,
                                         (size_t)DIM * HID, (size_t)DIM * HID);
        dim3 g2(DIM / 32, HID / 32, NLAYERS * NLEVELS);
        conv_t_k<<<g2, 256, 0, stream>>>(w2, w2H, w2L, HID, DIM,
                                         (size_t)DIM * HID, (size_t)DIM * HID);
    }

    embed_k<<<SD / 256, 256, 0, stream>>>(tok, pos, ids, x);

    const dim3 gqkv(3 * DIM / 64, SQL / 128);      // (24, 16)  BN=64
    const dim3 g512(DIM / 64, SQL / 64);           // (8, 32)   [split-K kernel]
    const dim3 gw1(HID / 64, SQL / 128);           // (32, 16)  BN=64
    const dim3 ghead(SQL / 128, (VOC + 127) / 128);// (16, 393) M-fastest, BN=128
    const int RS = 3 * DIM;

    for (int l = 0; l < NLAYERS; ++l) {
        // --- attention block ---
        ln_k<<<SQL, 256, 0, stream>>>(x, xnH, xnL, ln1w + l * DIM, ln1b + l * DIM);
        // fused QKV: N = 1536, fmap on cols < 1024 (q,k)
        gemm_t<3, false, false, false, true, false, 64><<<gqkv, 256, 0, stream>>>(
            xnH, xnL, wqkvH + (size_t)l * 3 * DD, wqkvL + (size_t)l * 3 * DD,
            nullptr, nullptr, qkv, nullptr, nullptr, SQL, 3 * DIM, DIM, 2 * DIM);
        attn_p1<<<NHEADS * NCHUNK, 256, 0, stream>>>(qkv + DIM, qkv + 2 * DIM, Mc, ksm, RS);
        attn_scan<<<NHEADS * 65, 64, 0, stream>>>(Mc, ksm);
        attn_p3<<<NHEADS * NCHUNK, 256, 0, stream>>>(
            qkv, qkv + DIM, qkv + 2 * DIM, Mc, ksm, aoH, aoL, RS);
        // x += ao @ wo
        gemm_ks<0, true, false><<<g512, 512, 0, stream>>>(
            aoH, aoL, woH + (size_t)l * DD, woL + (size_t)l * DD,
            nullptr, x, x, nullptr, nullptr, SQL, DIM, DIM, 0);

        // --- CMS block ---
        ln_k<<<SQL, 256, 0, stream>>>(x, xnH, xnL, ln2w + l * DIM, ln2b + l * DIM);
        const us* cH = xnH; const us* cL = xnL;
        for (int lvl = 0; lvl < NLEVELS; ++lvl) {
            const size_t off1 = (size_t)(l * NLEVELS + lvl) * DIM * HID;
            const float* b1p = b1 + (size_t)(l * NLEVELS + lvl) * HID;
            const float* b2p = b2 + (size_t)(l * NLEVELS + lvl) * DIM;
            gemm_t<2, false, true, false, true, false, 64><<<gw1, 256, 0, stream>>>(
                cH, cL, w1H + off1, w1L + off1, b1p, nullptr,
                nullptr, h1H, h1L, SQL, HID, DIM, 0);
            if (lvl < NLEVELS - 1) {
                gemm_ks<0, false, true><<<g512, 512, 0, stream>>>(
                    h1H, h1L, w2H + off1, w2L + off1, b2p, nullptr,
                    nullptr, cinH, cinL, SQL, DIM, HID, 0);
                cH = cinH; cL = cinL;
            } else {
                // fuse residual: x += level_out
                gemm_ks<0, true, false><<<g512, 512, 0, stream>>>(
                    h1H, h1L, w2H + off1, w2L + off1, b2p, x,
                    x, nullptr, nullptr, SQL, DIM, HID, 0);
            }
        }
    }

    // --- final LN + tied head ---
    ln_k<<<SQL, 256, 0, stream>>>(x, xnH, xnL, lnfw, lnfb);
    // head: bf16x2 (drop a*lo_b term), BN=128, M-fastest grid (no XCD swizzle)
    gemm_t<0, false, false, true, false, true, 128><<<ghead, 256, 0, stream>>>(
        xnH, xnL, tokH, nullptr, nullptr, nullptr,
        outp, nullptr, nullptr, SQL, VOC, DIM, 0);
}